// Round 2
// baseline (4013.800 us; speedup 1.0000x reference)
//
#include <hip/hip_runtime.h>
#include <hip/hip_bf16.h>

#define B 128
#define T 64
#define E 512
#define H 512
#define AA 512
#define V 10000
#define NPAD 10112   // 79*128

typedef __hip_bfloat16 bf16;
typedef __attribute__((ext_vector_type(8))) short bf16x8s;
typedef __attribute__((ext_vector_type(4))) short s16x4;
typedef __attribute__((ext_vector_type(4))) float f32x4;

#define MFMA __builtin_amdgcn_mfma_f32_16x16x32_bf16

__device__ __forceinline__ bf16x8s ld8(const bf16* p) {
  return *reinterpret_cast<const bf16x8s*>(p);
}
__device__ __forceinline__ float sigm(float x) { return 1.f / (1.f + __expf(-x)); }
__device__ __forceinline__ float bf2f(unsigned short u) {
  return __uint_as_float(((unsigned)u) << 16);
}

// ---------------- grid barrier (32 co-resident blocks) ----------------
__device__ __forceinline__ void gbar(int* cnt, int target) {
  __syncthreads();
  if (threadIdx.x == 0) {
    __threadfence();
    __hip_atomic_fetch_add(cnt, 1, __ATOMIC_RELAXED, __HIP_MEMORY_SCOPE_AGENT);
    while (__hip_atomic_load(cnt, __ATOMIC_RELAXED, __HIP_MEMORY_SCOPE_AGENT) < target)
      __builtin_amdgcn_s_sleep(2);
    __threadfence();
  }
  __syncthreads();
  __threadfence();
}

// ---------------- prep kernels ----------------

__global__ __launch_bounds__(256) void kxs(const float* __restrict__ feat,
                                           const int* __restrict__ cap,
                                           const float* __restrict__ embW,
                                           bf16* __restrict__ xs) {
  int idx = blockIdx.x * 256 + threadIdx.x;   // B*T*E/4
  int e4 = (idx & 127) << 2;
  int b = (idx >> 7) & 127;
  int t = idx >> 14;
  const float* src = (t == 0) ? (feat + (size_t)b * E)
                              : (embW + (size_t)cap[b * (T - 1) + (t - 1)] * E);
  float4 v = *reinterpret_cast<const float4*>(src + e4);
  bf16* d = xs + ((size_t)t * B + b) * E + e4;
  d[0] = __float2bfloat16(v.x); d[1] = __float2bfloat16(v.y);
  d[2] = __float2bfloat16(v.z); d[3] = __float2bfloat16(v.w);
}

__global__ __launch_bounds__(256) void kcast(const float* __restrict__ s,
                                             bf16* __restrict__ d, int n4) {
  int i = blockIdx.x * 256 + threadIdx.x;
  if (i >= n4) return;
  float4 v = *reinterpret_cast<const float4*>(s + (size_t)i * 4);
  d[i * 4 + 0] = __float2bfloat16(v.x); d[i * 4 + 1] = __float2bfloat16(v.y);
  d[i * 4 + 2] = __float2bfloat16(v.z); d[i * 4 + 3] = __float2bfloat16(v.w);
}

// slice-cast: dst[r][0:512] = src[r][c0:c0+512], src ld=1024, R=512
__global__ __launch_bounds__(256) void kslice(const float* __restrict__ src,
                                              bf16* __restrict__ dst, int c0) {
  int i = blockIdx.x * 256 + threadIdx.x;   // 512*128
  int row = i >> 7, c4 = (i & 127) << 2;
  float4 v = *reinterpret_cast<const float4*>(src + (size_t)row * 1024 + c0 + c4);
  bf16* d = dst + (size_t)row * 512 + c4;
  d[0] = __float2bfloat16(v.x); d[1] = __float2bfloat16(v.y);
  d[2] = __float2bfloat16(v.z); d[3] = __float2bfloat16(v.w);
}

// transpose-cast: dst[a][e2] = src[e2][coff+a]; src (512 x ld1024)
__global__ __launch_bounds__(256) void ktrans(const float* __restrict__ src,
                                              bf16* __restrict__ dst, int coff) {
  __shared__ float tl[32][33];
  int bx = blockIdx.x & 15, by = blockIdx.x >> 4;
  int tx = threadIdx.x & 31, ty = threadIdx.x >> 5;
  for (int yy = ty; yy < 32; yy += 8)
    tl[yy][tx] = src[(size_t)(by * 32 + yy) * 1024 + coff + bx * 32 + tx];
  __syncthreads();
  for (int yy = ty; yy < 32; yy += 8)
    dst[(size_t)(bx * 32 + yy) * 512 + by * 32 + tx] = __float2bfloat16(tl[tx][yy]);
}

__global__ __launch_bounds__(256) void kpadW(const float* __restrict__ s,
                                             bf16* __restrict__ d) {
  int i = blockIdx.x * 256 + threadIdx.x;   // NPAD*H/4
  int row = (i << 2) / H;
  float4 v = make_float4(0.f, 0.f, 0.f, 0.f);
  if (row < V) v = *reinterpret_cast<const float4*>(s + (size_t)i * 4);
  d[i * 4 + 0] = __float2bfloat16(v.x); d[i * 4 + 1] = __float2bfloat16(v.y);
  d[i * 4 + 2] = __float2bfloat16(v.z); d[i * 4 + 3] = __float2bfloat16(v.w);
}

// gb0 = b_ih+b_hh ; gbA = gb0 + W_ih @ attd_b
__global__ __launch_bounds__(256) void kgb(const float* __restrict__ bih,
                                           const float* __restrict__ bhh,
                                           const float* __restrict__ Wih_f,
                                           const float* __restrict__ attdb,
                                           float* __restrict__ gb0,
                                           float* __restrict__ gbA) {
  int g = blockIdx.x * 256 + threadIdx.x;
  if (g >= 2048) return;
  float b0 = bih[g] + bhh[g];
  float s = 0.f;
  for (int e = 0; e < 512; ++e) s += Wih_f[(size_t)g * 512 + e] * attdb[e];
  gb0[g] = b0; gbA[g] = b0 + s;
}

// ---------------- m97-style GEMM: C[M,N] = A[M,512] @ Bw[N,512]^T ----------------
// EPI 0: fp32 out (stride V), +bias, masked by t<len, col<V
// EPI 1: bf16 out (stride Nld), +bias if non-null
template<int EPI>
__global__ __launch_bounds__(256) void kgemm(const bf16* __restrict__ Ag,
                                             const bf16* __restrict__ Bg,
                                             const float* __restrict__ bias,
                                             const int* __restrict__ len,
                                             float* __restrict__ outF,
                                             bf16* __restrict__ outB,
                                             int nbn, int Nld) {
  __shared__ __align__(16) char lds[2][2][16384];   // [buf][A/B][128 rows x 64 bf16]
  const int nwg = gridDim.x;
  const int bid0 = blockIdx.x;
  const int wg = (bid0 & 7) * (nwg >> 3) + (bid0 >> 3);   // XCD swizzle (nwg % 8 == 0)
  const int bm = wg / nbn, bn = wg % nbn;
  const int tid = threadIdx.x, w = tid >> 6, lane = tid & 63;
  const int fr = lane & 15, fq = lane >> 4, ko = fq << 3;
  const int mh = w >> 1, nh = w & 1;
  const bf16* Abase = Ag + (size_t)bm * 128 * 512;
  const bf16* Bbase = Bg + (size_t)bn * 128 * 512;

  f32x4 acc[4][4] = {};

  auto STAGE = [&](int buf, int k0) {
    #pragma unroll
    for (int it = 0; it < 4; ++it) {
      int si = tid + it * 256;
      int row = si >> 3;
      int s = (si & 7) ^ (row & 7);
      __builtin_amdgcn_global_load_lds(
        (const __attribute__((address_space(1))) void*)(Abase + (size_t)row * 512 + k0 + s * 8),
        (__attribute__((address_space(3))) void*)(&lds[buf][0][((tid & ~63) + it * 256) * 16]),
        16, 0, 0);
    }
    #pragma unroll
    for (int it = 0; it < 4; ++it) {
      int si = tid + it * 256;
      int row = si >> 3;
      int s = (si & 7) ^ (row & 7);
      __builtin_amdgcn_global_load_lds(
        (const __attribute__((address_space(1))) void*)(Bbase + (size_t)row * 512 + k0 + s * 8),
        (__attribute__((address_space(3))) void*)(&lds[buf][1][((tid & ~63) + it * 256) * 16]),
        16, 0, 0);
    }
  };

  STAGE(0, 0);
  __syncthreads();
  for (int kt = 0; kt < 8; ++kt) {
    int cur = kt & 1;
    if (kt < 7) STAGE(cur ^ 1, (kt + 1) * 64);
    #pragma unroll
    for (int kk = 0; kk < 64; kk += 32) {
      bf16x8s a[4], b[4];
      #pragma unroll
      for (int i = 0; i < 4; ++i) {
        int ra = mh * 64 + i * 16 + fr;
        a[i] = *reinterpret_cast<const bf16x8s*>(
            &lds[cur][0][ra * 128 + ((((kk + ko) >> 3) ^ (ra & 7)) << 4)]);
        int rb = nh * 64 + i * 16 + fr;
        b[i] = *reinterpret_cast<const bf16x8s*>(
            &lds[cur][1][rb * 128 + ((((kk + ko) >> 3) ^ (rb & 7)) << 4)]);
      }
      #pragma unroll
      for (int mi = 0; mi < 4; ++mi)
        #pragma unroll
        for (int ni = 0; ni < 4; ++ni)
          acc[mi][ni] = MFMA(a[mi], b[ni], acc[mi][ni], 0, 0, 0);
    }
    __syncthreads();
  }

  #pragma unroll
  for (int mi = 0; mi < 4; ++mi)
    #pragma unroll
    for (int ni = 0; ni < 4; ++ni)
      #pragma unroll
      for (int j = 0; j < 4; ++j) {
        int row = bm * 128 + mh * 64 + mi * 16 + fq * 4 + j;
        int col = bn * 128 + nh * 64 + ni * 16 + fr;
        if (EPI == 0) {
          if (col < V) {
            int tt = row >> 7, bb = row & 127;
            outF[(size_t)row * V + col] = (tt < len[bb]) ? acc[mi][ni][j] + bias[col] : 0.f;
          }
        } else {
          float bv = bias ? bias[col] : 0.f;
          outB[(size_t)row * Nld + col] = __float2bfloat16(acc[mi][ni][j] + bv);
        }
      }
}

// ---------------- persistent sequential loop ----------------
// 32 blocks x 512 threads. Per step t>=1:
//   gbar; phase1: S_h=h@WaH^T (+Sx) -> P'=exp*cnn, Z; gbar; phase2: gates=Gx+(P'@Kc^T)/Z+h@Whh^T+gb -> cell
// t=0: phase2 only with gates=Gx[0]+gb0.
__global__ __launch_bounds__(512, 1) void kloop(
    const bf16* __restrict__ Sxb,    // [T][B][512]
    const bf16* __restrict__ Gx,     // [T][B][2048]
    const bf16* __restrict__ Kc,     // [2048][512]
    const bf16* __restrict__ Whh,    // [2048][512]
    const bf16* __restrict__ WaH,    // [512][512]
    const float* __restrict__ gb0,
    const float* __restrict__ gbA,
    const float* __restrict__ cnn,   // [B][512] f32
    const int* __restrict__ len,
    bf16* __restrict__ h0,
    bf16* __restrict__ h1,
    float* __restrict__ cst,         // [B][512]
    bf16* __restrict__ pbuf,         // [B][512]
    float* __restrict__ Zbuf,        // [T][B]
    bf16* __restrict__ hid,          // [T][B][512]
    int* __restrict__ cnt) {
  __shared__ float smem[8704];       // p1: [8][32][33]  p2: [4][64][34]
  const int tid = threadIdx.x, w = tid >> 6, lane = tid & 63;
  const int fr = lane & 15, fq = lane >> 4, ko = fq << 3;
  const int bid = blockIdx.x;
  // phase1: block = (m: 4x32 rows) x (n: 8x64 cols); wave = (ntile, kquarter)
  const int p1m = (bid & 3) << 5;
  const int p1n = (bid >> 2) << 6;
  const int p1nt = w & 1, p1kq = w >> 1;
  // phase2: block = (m: 2x64 rows) x (j: 16x32 h-cols); wave = (quarter, nhalf)
  const int p2m = (bid & 1) << 6;
  const int p2j = (bid >> 1) << 5;
  const int p2q = w >> 1, p2nh = w & 1;
  const int gc0 = p2q * 512 + p2j + p2nh * 16;

  int ep = 0;
  for (int t = 0; t < T; ++t) {
    const bf16* hin = (t & 1) ? h1 : h0;
    bf16* hout = (t & 1) ? h0 : h1;
    if (t) {
      gbar(cnt, 32 * (++ep));        // h ready
      // ---- phase 1 ----
      {
        f32x4 acc[2][2] = {};
        const bf16* ha = hin + (size_t)(p1m + fr) * H + p1kq * 128 + ko;
        const bf16* wb = WaH + (size_t)(p1n + p1nt * 32 + fr) * H + p1kq * 128 + ko;
        #pragma unroll
        for (int k = 0; k < 128; k += 32) {
          bf16x8s a0 = ld8(ha + k), a1 = ld8(ha + 16 * H + k);
          bf16x8s b0 = ld8(wb + k), b1 = ld8(wb + 16 * H + k);
          acc[0][0] = MFMA(a0, b0, acc[0][0], 0, 0, 0);
          acc[0][1] = MFMA(a0, b1, acc[0][1], 0, 0, 0);
          acc[1][0] = MFMA(a1, b0, acc[1][0], 0, 0, 0);
          acc[1][1] = MFMA(a1, b1, acc[1][1], 0, 0, 0);
        }
        #pragma unroll
        for (int mi = 0; mi < 2; ++mi)
          #pragma unroll
          for (int ni = 0; ni < 2; ++ni)
            #pragma unroll
            for (int j = 0; j < 4; ++j)
              smem[w * 1056 + (mi * 16 + fq * 4 + j) * 33 + ni * 16 + fr] = acc[mi][ni][j];
      }
      __syncthreads();
      {
        int nt2 = tid >> 8, idx = tid & 255;
        int rw = idx >> 3, c0 = (idx & 7) << 2;
        int grow = p1m + rw;
        int gcol = p1n + nt2 * 32 + c0;
        s16x4 sx = *reinterpret_cast<const s16x4*>(Sxb + ((size_t)t * B + grow) * AA + gcol);
        float4 cv = *reinterpret_cast<const float4*>(cnn + (size_t)grow * AA + gcol);
        const float* cvp = reinterpret_cast<const float*>(&cv);
        float z = 0.f;
        s16x4 pv;
        #pragma unroll
        for (int c = 0; c < 4; ++c) {
          float s = 0.f;
          #pragma unroll
          for (int kq = 0; kq < 4; ++kq)
            s += smem[(kq * 2 + nt2) * 1056 + rw * 33 + c0 + c];
          float p = __expf(s + bf2f((unsigned short)sx[c]));
          z += p;
          bf16 pb = __float2bfloat16(p * cvp[c]);
          pv[c] = *reinterpret_cast<const short*>(&pb);
        }
        *reinterpret_cast<s16x4*>(pbuf + (size_t)grow * AA + gcol) = pv;
        z += __shfl_down(z, 4); z += __shfl_down(z, 2); z += __shfl_down(z, 1);
        if ((idx & 7) == 0) atomicAdd(Zbuf + t * B + grow, z);
      }
      gbar(cnt, 32 * (++ep));        // P', Z ready
    }
    // ---- phase 2 ----
    f32x4 acc[4] = {};
    if (t) {
      const bf16* pa = pbuf + (size_t)(p2m + fr) * AA + ko;
      const bf16* kb = Kc + (size_t)(gc0 + fr) * AA + ko;
      #pragma unroll 4
      for (int k = 0; k < 512; k += 32) {
        bf16x8s bv = ld8(kb + k);
        #pragma unroll
        for (int mi = 0; mi < 4; ++mi)
          acc[mi] = MFMA(ld8(pa + mi * 16 * AA + k), bv, acc[mi], 0, 0, 0);
      }
      #pragma unroll
      for (int mi = 0; mi < 4; ++mi)
        #pragma unroll
        for (int j = 0; j < 4; ++j)
          acc[mi][j] *= __fdividef(1.f, Zbuf[t * B + p2m + mi * 16 + fq * 4 + j]);
      const bf16* ha = hin + (size_t)(p2m + fr) * H + ko;
      const bf16* wb = Whh + (size_t)(gc0 + fr) * H + ko;
      #pragma unroll 4
      for (int k = 0; k < 512; k += 32) {
        bf16x8s bv = ld8(wb + k);
        #pragma unroll
        for (int mi = 0; mi < 4; ++mi)
          acc[mi] = MFMA(ld8(ha + mi * 16 * H + k), bv, acc[mi], 0, 0, 0);
      }
    }
    {
      const float* gb = t ? gbA : gb0;
      #pragma unroll
      for (int mi = 0; mi < 4; ++mi)
        #pragma unroll
        for (int j = 0; j < 4; ++j) {
          int rw = mi * 16 + fq * 4 + j;
          int grow = p2m + rw;
          int gcol = gc0 + fr;
          float v = acc[mi][j] + gb[gcol] +
              bf2f(*reinterpret_cast<const unsigned short*>(Gx + ((size_t)t * B + grow) * 2048 + gcol));
          smem[p2q * 2176 + rw * 34 + p2nh * 16 + fr] = v;
        }
    }
    __syncthreads();
    {
      int rw = tid >> 3, c0 = (tid & 7) << 2;
      int grow = p2m + rw;
      bool act = t < len[grow];
      #pragma unroll
      for (int c = 0; c < 4; ++c) {
        int jl = c0 + c;
        float gi = sigm(smem[0 * 2176 + rw * 34 + jl]);
        float gf = sigm(smem[1 * 2176 + rw * 34 + jl]);
        float gg = tanhf(smem[2 * 2176 + rw * 34 + jl]);
        float go = sigm(smem[3 * 2176 + rw * 34 + jl]);
        int jg = p2j + jl;
        float cold = cst[(size_t)grow * H + jg];
        float c2 = gf * cold + gi * gg;
        float h2v = go * tanhf(c2);
        if (act) cst[(size_t)grow * H + jg] = c2;
        bf16 hp = hin[(size_t)grow * H + jg];
        hout[(size_t)grow * H + jg] = act ? __float2bfloat16(h2v) : hp;
        hid[((size_t)t * B + grow) * H + jg] = act ? __float2bfloat16(h2v)
                                                   : __float2bfloat16(0.f);
      }
    }
    __syncthreads();
  }
}

// ---------------- launch ----------------

extern "C" void kernel_launch(void* const* d_in, const int* in_sizes, int n_in,
                              void* d_out, int out_size, void* d_ws, size_t ws_size,
                              hipStream_t stream) {
  const float* feat   = (const float*)d_in[0];
  const int*   cap    = (const int*)d_in[1];
  const int*   len    = (const int*)d_in[2];
  const float* cnn    = (const float*)d_in[3];
  const float* embW   = (const float*)d_in[4];
  const float* Wih_f  = (const float*)d_in[5];
  const float* Whh_f  = (const float*)d_in[6];
  const float* bih    = (const float*)d_in[7];
  const float* bhh    = (const float*)d_in[8];
  const float* attW_f = (const float*)d_in[9];
  const float* attb   = (const float*)d_in[10];
  const float* attdW_f= (const float*)d_in[11];
  const float* attdb  = (const float*)d_in[12];
  const float* outW_f = (const float*)d_in[13];
  const float* outb   = (const float*)d_in[14];
  float* out = (float*)d_out;
  char* ws = (char*)d_ws;

  size_t off = 0;
  auto alloc = [&](size_t n) { char* p = ws + off; off += (n + 255) & ~(size_t)255; return p; };
  bf16*  xs    = (bf16*)alloc(8388608);
  bf16*  WaX   = (bf16*)alloc(524288);
  bf16*  WaH   = (bf16*)alloc(524288);
  bf16*  WdXT  = (bf16*)alloc(524288);
  bf16*  WdAT  = (bf16*)alloc(524288);
  bf16*  Wihb  = (bf16*)alloc(2097152);
  bf16*  Whhb  = (bf16*)alloc(2097152);
  bf16*  Kx    = (bf16*)alloc(2097152);
  bf16*  Kc    = (bf16*)alloc(2097152);
  bf16*  outWp = (bf16*)alloc(10354688);
  bf16*  Sxb   = (bf16*)alloc(8388608);
  bf16*  Gx    = (bf16*)alloc(33554432);
  bf16*  hid   = (bf16*)alloc(8388608);
  float* gb0   = (float*)alloc(8192);
  float* gbA   = (float*)alloc(8192);
  bf16*  h0    = (bf16*)alloc(131072);
  bf16*  h1    = (bf16*)alloc(131072);
  float* cst   = (float*)alloc(262144);
  bf16*  pbuf  = (bf16*)alloc(131072);
  float* Zbuf  = (float*)alloc(32768);
  int*   cnt   = (int*)alloc(256);

  kxs<<<4096, 256, 0, stream>>>(feat, cap, embW, xs);
  kslice<<<256, 256, 0, stream>>>(attW_f, WaX, 0);
  kslice<<<256, 256, 0, stream>>>(attW_f, WaH, 512);
  ktrans<<<256, 256, 0, stream>>>(attdW_f, WdXT, 0);
  ktrans<<<256, 256, 0, stream>>>(attdW_f, WdAT, 512);
  kcast<<<1024, 256, 0, stream>>>(Wih_f, Wihb, 262144);
  kcast<<<1024, 256, 0, stream>>>(Whh_f, Whhb, 262144);
  kpadW<<<5056, 256, 0, stream>>>(outW_f, outWp);
  kgb<<<8, 256, 0, stream>>>(bih, bhh, Wih_f, attdb, gb0, gbA);

  // precompute GEMMs (all K=512, A@B^T form)
  kgemm<1><<<256, 256, 0, stream>>>(xs, WaX, attb, nullptr, nullptr, Sxb, 4, 512);
  kgemm<1><<<64, 256, 0, stream>>>(Wihb, WdXT, nullptr, nullptr, nullptr, Kx, 4, 512);
  kgemm<1><<<64, 256, 0, stream>>>(Wihb, WdAT, nullptr, nullptr, nullptr, Kc, 4, 512);
  kgemm<1><<<1024, 256, 0, stream>>>(xs, Kx, nullptr, nullptr, nullptr, Gx, 16, 2048);
  kgemm<1><<<16, 256, 0, stream>>>(xs, Wihb, nullptr, nullptr, nullptr, Gx, 16, 2048); // t=0 rows

  hipMemsetAsync(cnt, 0, 256, stream);
  hipMemsetAsync(Zbuf, 0, 32768, stream);
  hipMemsetAsync(cst, 0, 262144, stream);
  hipMemsetAsync(h0, 0, 131072, stream);

  kloop<<<32, 512, 0, stream>>>(Sxb, Gx, Kc, Whhb, WaH, gb0, gbA, cnn, len,
                                h0, h1, cst, pbuf, Zbuf, hid, cnt);

  kgemm<0><<<5056, 256, 0, stream>>>(hid, outWp, outb, len, out, nullptr, 79, V);
}